// Round 13
// baseline (273.962 us; speedup 1.0000x reference)
//
#include <hip/hip_runtime.h>

#define IN_F 128
#define OUT_F 64
typedef unsigned int u32;

// ---------------------------------------------------------------------------
// Kernel 1: sp = x @ W. 64x64 tile per block (256 thr), 4 rows x 4 cols per
// thread. k-loop unroll CAPPED at 2 (full unroll spilled ~4KB/thread of
// hoisted LDS loads -> 2.9 GB HBM scratch traffic, rounds 5/6).
// ---------------------------------------------------------------------------
__global__ __launch_bounds__(256, 2) void gemm_xw(
    const float* __restrict__ x, const float* __restrict__ W,
    float* __restrict__ sp, int n_nodes)
{
    __shared__ float Wlds[IN_F * OUT_F];     // 32 KB, [k][j]
    __shared__ float xlds[64][IN_F + 4];     // 33.8 KB, stride 132 (pad)

    const int t = threadIdx.x;
    const int row0 = blockIdx.x * 64;

    #pragma unroll
    for (int j = 0; j < 8; ++j) {
        const int off = j * 1024 + t * 4;
        *(float4*)&Wlds[off] = *(const float4*)&W[off];
    }
    #pragma unroll
    for (int j = 0; j < 8; ++j) {
        const int off = j * 1024 + t * 4;
        const int r = off >> 7, k = off & 127;
        if (row0 + r < n_nodes)
            *(float4*)&xlds[r][k] = *(const float4*)&x[(size_t)row0 * IN_F + off];
    }
    __syncthreads();

    const int ty = t >> 4;
    const int tx = (t & 15) * 4;

    float4 a0 = {0,0,0,0};
    float4 a1 = {0,0,0,0};
    float4 a2 = {0,0,0,0};
    float4 a3 = {0,0,0,0};

    #pragma unroll 2
    for (int k = 0; k < IN_F; k += 4) {
        const float4 w0 = *(const float4*)&Wlds[(k + 0) * OUT_F + tx];
        const float4 w1 = *(const float4*)&Wlds[(k + 1) * OUT_F + tx];
        const float4 w2 = *(const float4*)&Wlds[(k + 2) * OUT_F + tx];
        const float4 w3 = *(const float4*)&Wlds[(k + 3) * OUT_F + tx];
        const float4 x0 = *(const float4*)&xlds[ty * 4 + 0][k];
        const float4 x1 = *(const float4*)&xlds[ty * 4 + 1][k];
        const float4 x2 = *(const float4*)&xlds[ty * 4 + 2][k];
        const float4 x3 = *(const float4*)&xlds[ty * 4 + 3][k];

        a0.x += x0.x*w0.x + x0.y*w1.x + x0.z*w2.x + x0.w*w3.x;
        a0.y += x0.x*w0.y + x0.y*w1.y + x0.z*w2.y + x0.w*w3.y;
        a0.z += x0.x*w0.z + x0.y*w1.z + x0.z*w2.z + x0.w*w3.z;
        a0.w += x0.x*w0.w + x0.y*w1.w + x0.z*w2.w + x0.w*w3.w;

        a1.x += x1.x*w0.x + x1.y*w1.x + x1.z*w2.x + x1.w*w3.x;
        a1.y += x1.x*w0.y + x1.y*w1.y + x1.z*w2.y + x1.w*w3.y;
        a1.z += x1.x*w0.z + x1.y*w1.z + x1.z*w2.z + x1.w*w3.z;
        a1.w += x1.x*w0.w + x1.y*w1.w + x1.z*w2.w + x1.w*w3.w;

        a2.x += x2.x*w0.x + x2.y*w1.x + x2.z*w2.x + x2.w*w3.x;
        a2.y += x2.x*w0.y + x2.y*w1.y + x2.z*w2.y + x2.w*w3.y;
        a2.z += x2.x*w0.z + x2.y*w1.z + x2.z*w2.z + x2.w*w3.z;
        a2.w += x2.x*w0.w + x2.y*w1.w + x2.z*w2.w + x2.w*w3.w;

        a3.x += x3.x*w0.x + x3.y*w1.x + x3.z*w2.x + x3.w*w3.x;
        a3.y += x3.x*w0.y + x3.y*w1.y + x3.z*w2.y + x3.w*w3.y;
        a3.z += x3.x*w0.z + x3.y*w1.z + x3.z*w2.z + x3.w*w3.z;
        a3.w += x3.x*w0.w + x3.y*w1.w + x3.z*w2.w + x3.w*w3.w;
    }

    const int rowBase = row0 + ty * 4;
    if (rowBase + 0 < n_nodes) *(float4*)&sp[(size_t)(rowBase + 0) * OUT_F + tx] = a0;
    if (rowBase + 1 < n_nodes) *(float4*)&sp[(size_t)(rowBase + 1) * OUT_F + tx] = a1;
    if (rowBase + 2 < n_nodes) *(float4*)&sp[(size_t)(rowBase + 2) * OUT_F + tx] = a2;
    if (rowBase + 3 < n_nodes) *(float4*)&sp[(size_t)(rowBase + 3) * OUT_F + tx] = a3;
}

// ---------------------------------------------------------------------------
// Counting sort of edges by row: hist -> scan (3 kernels) -> scatter.
// ---------------------------------------------------------------------------
__global__ __launch_bounds__(256) void hist_rows(
    const int* __restrict__ rows, u32* __restrict__ counts, int n_edges)
{
    const int e = blockIdx.x * 256 + threadIdx.x;
    if (e < n_edges) atomicAdd(&counts[rows[e]], 1u);
}

__global__ __launch_bounds__(256) void scan1(
    const u32* __restrict__ counts, u32* __restrict__ partial,
    u32* __restrict__ blockSums, int n)
{
    __shared__ u32 sdata[256];
    const int t = threadIdx.x;
    const int base = blockIdx.x * 2048 + t * 8;
    u32 v[8], s = 0;
    #pragma unroll
    for (int j = 0; j < 8; ++j) { v[j] = (base + j < n) ? counts[base + j] : 0u; s += v[j]; }
    sdata[t] = s;
    __syncthreads();
    for (int off = 1; off < 256; off <<= 1) {
        u32 xv = (t >= off) ? sdata[t - off] : 0u;
        __syncthreads();
        sdata[t] += xv;
        __syncthreads();
    }
    const u32 excl = sdata[t] - s;
    if (t == 255) blockSums[blockIdx.x] = sdata[255];
    u32 run = excl;
    #pragma unroll
    for (int j = 0; j < 8; ++j) { if (base + j < n) partial[base + j] = run; run += v[j]; }
}

__global__ __launch_bounds__(256) void scan2(u32* __restrict__ blockSums, int nb)
{
    __shared__ u32 sdata[256];
    const int t = threadIdx.x;
    const u32 v = (t < nb) ? blockSums[t] : 0u;
    sdata[t] = v;
    __syncthreads();
    for (int off = 1; off < 256; off <<= 1) {
        u32 xv = (t >= off) ? sdata[t - off] : 0u;
        __syncthreads();
        sdata[t] += xv;
        __syncthreads();
    }
    if (t < nb) blockSums[t] = sdata[t] - v;
}

__global__ __launch_bounds__(256) void scan3(
    u32* __restrict__ offsets, const u32* __restrict__ blockSums,
    u32* __restrict__ cursors, int n, int total)
{
    const int i = blockIdx.x * 256 + threadIdx.x;
    if (i < n) {
        const u32 o = offsets[i] + blockSums[i >> 11];
        offsets[i] = o;
        cursors[i] = o;
    }
    if (i == n) offsets[n] = (u32)total;
}

// Single packed 8B store per edge: one row's ~8 edges share one 64B line
// (was 2x4B to two arrays -> 84.5 MB HBM writes for a 6.4 MB payload).
__global__ __launch_bounds__(256) void sort_scatter(
    const int* __restrict__ rows, const int* __restrict__ cols,
    const float* __restrict__ vals, u32* __restrict__ cursors,
    int2* __restrict__ edat, int n_edges)
{
    const int e = blockIdx.x * 256 + threadIdx.x;
    if (e >= n_edges) return;
    const u32 p = atomicAdd(&cursors[rows[e]], 1u);
    int2 d;
    d.x = cols[e];
    d.y = __float_as_int(vals[e]);
    edat[p] = d;
}

// ---------------------------------------------------------------------------
// Aggregate: one wave per row. lane j = feature j. Packed (col,val) loads are
// wave-uniform 8B broadcasts; sp gathers are coalesced 256B/edge. No atomics.
// ---------------------------------------------------------------------------
__global__ __launch_bounds__(256) void aggregate(
    const int2* __restrict__ edat, const u32* __restrict__ offsets,
    const float* __restrict__ sp, const float* __restrict__ bias,
    float* __restrict__ out, int n_nodes)
{
    const int wid = (blockIdx.x * 256 + threadIdx.x) >> 6;   // row
    const int lane = threadIdx.x & 63;
    if (wid >= n_nodes) return;
    const int beg = __builtin_amdgcn_readfirstlane((int)offsets[wid]);
    const int end = __builtin_amdgcn_readfirstlane((int)offsets[wid + 1]);

    float acc = bias[lane];
    int i = beg;
    for (; i + 1 < end; i += 2) {
        const int2 d0 = edat[i];
        const int2 d1 = edat[i + 1];
        const float s0 = sp[(size_t)d0.x * OUT_F + lane];
        const float s1 = sp[(size_t)d1.x * OUT_F + lane];
        acc += __int_as_float(d0.y) * s0;
        acc += __int_as_float(d1.y) * s1;
    }
    if (i < end) {
        const int2 d = edat[i];
        acc += __int_as_float(d.y) * sp[(size_t)d.x * OUT_F + lane];
    }
    out[(size_t)wid * OUT_F + lane] = acc;
}

// ---------------------------------------------------------------------------
extern "C" void kernel_launch(void* const* d_in, const int* in_sizes, int n_in,
                              void* d_out, int out_size, void* d_ws, size_t ws_size,
                              hipStream_t stream) {
    const float* x        = (const float*)d_in[0];
    const float* W        = (const float*)d_in[1];
    const float* bias     = (const float*)d_in[2];
    const int*   adj_rows = (const int*)d_in[3];
    const int*   adj_cols = (const int*)d_in[4];
    const float* adj_vals = (const float*)d_in[5];
    float* out = (float*)d_out;

    const int n_nodes = in_sizes[0] / IN_F;
    const int n_edges = in_sizes[3];

    // Workspace layout (edat first after sp for 8B alignment), ~33.2 MB:
    char* ws = (char*)d_ws;
    float* sp       = (float*)ws;                                   // n_nodes*64 f32
    int2*  edat     = (int2*)(ws + (size_t)n_nodes * OUT_F * 4);    // n_edges int2
    u32*   counts   = (u32*)(edat + n_edges);                       // n_nodes
    u32*   offsets  = counts + n_nodes;                             // n_nodes+1
    u32*   cursors  = offsets + n_nodes + 1;                        // n_nodes
    u32*   blockSums= cursors + n_nodes;                            // <=256

    // 1) sp = x @ W
    gemm_xw<<<(n_nodes + 63) / 64, 256, 0, stream>>>(x, W, sp, n_nodes);

    // 2) counting sort by row
    hipMemsetAsync(counts, 0, (size_t)n_nodes * 4, stream);
    hist_rows<<<(n_edges + 255) / 256, 256, 0, stream>>>(adj_rows, counts, n_edges);
    const int nb = (n_nodes + 2047) / 2048;
    scan1<<<nb, 256, 0, stream>>>(counts, offsets, blockSums, n_nodes);
    scan2<<<1, 256, 0, stream>>>(blockSums, nb);
    scan3<<<(n_nodes + 1 + 255) / 256, 256, 0, stream>>>(offsets, blockSums, cursors,
                                                         n_nodes, n_edges);
    sort_scatter<<<(n_edges + 255) / 256, 256, 0, stream>>>(
        adj_rows, adj_cols, adj_vals, cursors, edat, n_edges);

    // 3) per-row gather-aggregate (bias folded in, no atomics)
    aggregate<<<(n_nodes + 3) / 4, 256, 0, stream>>>(
        edat, offsets, sp, bias, out, n_nodes);
}

// Round 14
// 255.246 us; speedup vs baseline: 1.0733x; 1.0733x over previous
//
#include <hip/hip_runtime.h>

#define IN_F 128
#define OUT_F 64
#define EPT 8          // edges per thread in sort_scatter (ILP batching)
typedef unsigned int u32;

// ---------------------------------------------------------------------------
// Kernel 1: sp = x @ W. 64x64 tile per block (256 thr), 4 rows x 4 cols per
// thread. k-loop unroll CAPPED at 2 (full unroll spilled ~4KB/thread of
// hoisted LDS loads -> 2.9 GB HBM scratch traffic, rounds 5/6).
// ---------------------------------------------------------------------------
__global__ __launch_bounds__(256, 2) void gemm_xw(
    const float* __restrict__ x, const float* __restrict__ W,
    float* __restrict__ sp, int n_nodes)
{
    __shared__ float Wlds[IN_F * OUT_F];     // 32 KB, [k][j]
    __shared__ float xlds[64][IN_F + 4];     // 33.8 KB, stride 132 (pad)

    const int t = threadIdx.x;
    const int row0 = blockIdx.x * 64;

    #pragma unroll
    for (int j = 0; j < 8; ++j) {
        const int off = j * 1024 + t * 4;
        *(float4*)&Wlds[off] = *(const float4*)&W[off];
    }
    #pragma unroll
    for (int j = 0; j < 8; ++j) {
        const int off = j * 1024 + t * 4;
        const int r = off >> 7, k = off & 127;
        if (row0 + r < n_nodes)
            *(float4*)&xlds[r][k] = *(const float4*)&x[(size_t)row0 * IN_F + off];
    }
    __syncthreads();

    const int ty = t >> 4;
    const int tx = (t & 15) * 4;

    float4 a0 = {0,0,0,0};
    float4 a1 = {0,0,0,0};
    float4 a2 = {0,0,0,0};
    float4 a3 = {0,0,0,0};

    #pragma unroll 2
    for (int k = 0; k < IN_F; k += 4) {
        const float4 w0 = *(const float4*)&Wlds[(k + 0) * OUT_F + tx];
        const float4 w1 = *(const float4*)&Wlds[(k + 1) * OUT_F + tx];
        const float4 w2 = *(const float4*)&Wlds[(k + 2) * OUT_F + tx];
        const float4 w3 = *(const float4*)&Wlds[(k + 3) * OUT_F + tx];
        const float4 x0 = *(const float4*)&xlds[ty * 4 + 0][k];
        const float4 x1 = *(const float4*)&xlds[ty * 4 + 1][k];
        const float4 x2 = *(const float4*)&xlds[ty * 4 + 2][k];
        const float4 x3 = *(const float4*)&xlds[ty * 4 + 3][k];

        a0.x += x0.x*w0.x + x0.y*w1.x + x0.z*w2.x + x0.w*w3.x;
        a0.y += x0.x*w0.y + x0.y*w1.y + x0.z*w2.y + x0.w*w3.y;
        a0.z += x0.x*w0.z + x0.y*w1.z + x0.z*w2.z + x0.w*w3.z;
        a0.w += x0.x*w0.w + x0.y*w1.w + x0.z*w2.w + x0.w*w3.w;

        a1.x += x1.x*w0.x + x1.y*w1.x + x1.z*w2.x + x1.w*w3.x;
        a1.y += x1.x*w0.y + x1.y*w1.y + x1.z*w2.y + x1.w*w3.y;
        a1.z += x1.x*w0.z + x1.y*w1.z + x1.z*w2.z + x1.w*w3.z;
        a1.w += x1.x*w0.w + x1.y*w1.w + x1.z*w2.w + x1.w*w3.w;

        a2.x += x2.x*w0.x + x2.y*w1.x + x2.z*w2.x + x2.w*w3.x;
        a2.y += x2.x*w0.y + x2.y*w1.y + x2.z*w2.y + x2.w*w3.y;
        a2.z += x2.x*w0.z + x2.y*w1.z + x2.z*w2.z + x2.w*w3.z;
        a2.w += x2.x*w0.w + x2.y*w1.w + x2.z*w2.w + x2.w*w3.w;

        a3.x += x3.x*w0.x + x3.y*w1.x + x3.z*w2.x + x3.w*w3.x;
        a3.y += x3.x*w0.y + x3.y*w1.y + x3.z*w2.y + x3.w*w3.y;
        a3.z += x3.x*w0.z + x3.y*w1.z + x3.z*w2.z + x3.w*w3.z;
        a3.w += x3.x*w0.w + x3.y*w1.w + x3.z*w2.w + x3.w*w3.w;
    }

    const int rowBase = row0 + ty * 4;
    if (rowBase + 0 < n_nodes) *(float4*)&sp[(size_t)(rowBase + 0) * OUT_F + tx] = a0;
    if (rowBase + 1 < n_nodes) *(float4*)&sp[(size_t)(rowBase + 1) * OUT_F + tx] = a1;
    if (rowBase + 2 < n_nodes) *(float4*)&sp[(size_t)(rowBase + 2) * OUT_F + tx] = a2;
    if (rowBase + 3 < n_nodes) *(float4*)&sp[(size_t)(rowBase + 3) * OUT_F + tx] = a3;
}

// ---------------------------------------------------------------------------
// Counting sort of edges by row: hist -> scan (3 kernels) -> scatter.
// ---------------------------------------------------------------------------
__global__ __launch_bounds__(256) void hist_rows(
    const int* __restrict__ rows, u32* __restrict__ counts, int n_edges)
{
    const int e = blockIdx.x * 256 + threadIdx.x;
    if (e < n_edges) atomicAdd(&counts[rows[e]], 1u);
}

__global__ __launch_bounds__(256) void scan1(
    const u32* __restrict__ counts, u32* __restrict__ partial,
    u32* __restrict__ blockSums, int n)
{
    __shared__ u32 sdata[256];
    const int t = threadIdx.x;
    const int base = blockIdx.x * 2048 + t * 8;
    u32 v[8], s = 0;
    #pragma unroll
    for (int j = 0; j < 8; ++j) { v[j] = (base + j < n) ? counts[base + j] : 0u; s += v[j]; }
    sdata[t] = s;
    __syncthreads();
    for (int off = 1; off < 256; off <<= 1) {
        u32 xv = (t >= off) ? sdata[t - off] : 0u;
        __syncthreads();
        sdata[t] += xv;
        __syncthreads();
    }
    const u32 excl = sdata[t] - s;
    if (t == 255) blockSums[blockIdx.x] = sdata[255];
    u32 run = excl;
    #pragma unroll
    for (int j = 0; j < 8; ++j) { if (base + j < n) partial[base + j] = run; run += v[j]; }
}

__global__ __launch_bounds__(256) void scan2(u32* __restrict__ blockSums, int nb)
{
    __shared__ u32 sdata[256];
    const int t = threadIdx.x;
    const u32 v = (t < nb) ? blockSums[t] : 0u;
    sdata[t] = v;
    __syncthreads();
    for (int off = 1; off < 256; off <<= 1) {
        u32 xv = (t >= off) ? sdata[t - off] : 0u;
        __syncthreads();
        sdata[t] += xv;
        __syncthreads();
    }
    if (t < nb) blockSums[t] = sdata[t] - v;
}

__global__ __launch_bounds__(256) void scan3(
    u32* __restrict__ offsets, const u32* __restrict__ blockSums,
    u32* __restrict__ cursors, int n, int total)
{
    const int i = blockIdx.x * 256 + threadIdx.x;
    if (i < n) {
        const u32 o = offsets[i] + blockSums[i >> 11];
        offsets[i] = o;
        cursors[i] = o;
    }
    if (i == n) offsets[n] = (u32)total;
}

// ---------------------------------------------------------------------------
// Scatter with 8-deep ILP: rounds 7/13 showed time is INVARIANT to write
// traffic (84.5->53 MB, dur 60->65us) with nothing saturated -> latency-bound
// on the 1-edge-per-thread chain load->atomic(ret)->store. Batch 8 edges per
// thread: 8 independent loads, then 8 independent atomics, then 8 stores.
// All array indices compile-time after unroll (no scratch, rule #20).
// ---------------------------------------------------------------------------
__global__ __launch_bounds__(256) void sort_scatter(
    const int* __restrict__ rows, const int* __restrict__ cols,
    const float* __restrict__ vals, u32* __restrict__ cursors,
    int2* __restrict__ edat, int n_edges)
{
    const int tid = blockIdx.x * 256 + threadIdx.x;
    const int stride = gridDim.x * 256;

    int r0,r1,r2,r3,r4,r5,r6,r7;
    int c0,c1,c2,c3,c4,c5,c6,c7;
    float v0,v1,v2,v3,v4,v5,v6,v7;
    u32 p0,p1,p2,p3,p4,p5,p6,p7;

    // Phase 1: issue all loads (coalesced per j-slice, independent).
    #define LD(j, rr, cc, vv) { \
        const int e = tid + (j) * stride; \
        if (e < n_edges) { rr = rows[e]; cc = cols[e]; vv = vals[e]; } \
        else rr = -1; }
    LD(0,r0,c0,v0) LD(1,r1,c1,v1) LD(2,r2,c2,v2) LD(3,r3,c3,v3)
    LD(4,r4,c4,v4) LD(5,r5,c5,v5) LD(6,r6,c6,v6) LD(7,r7,c7,v7)
    #undef LD

    // Phase 2: 8 independent atomics (latency overlapped).
    if (r0 >= 0) p0 = atomicAdd(&cursors[r0], 1u);
    if (r1 >= 0) p1 = atomicAdd(&cursors[r1], 1u);
    if (r2 >= 0) p2 = atomicAdd(&cursors[r2], 1u);
    if (r3 >= 0) p3 = atomicAdd(&cursors[r3], 1u);
    if (r4 >= 0) p4 = atomicAdd(&cursors[r4], 1u);
    if (r5 >= 0) p5 = atomicAdd(&cursors[r5], 1u);
    if (r6 >= 0) p6 = atomicAdd(&cursors[r6], 1u);
    if (r7 >= 0) p7 = atomicAdd(&cursors[r7], 1u);

    // Phase 3: 8 independent packed stores.
    #define ST(rr, cc, vv, pp) \
        if (rr >= 0) { int2 d; d.x = cc; d.y = __float_as_int(vv); edat[pp] = d; }
    ST(r0,c0,v0,p0) ST(r1,c1,v1,p1) ST(r2,c2,v2,p2) ST(r3,c3,v3,p3)
    ST(r4,c4,v4,p4) ST(r5,c5,v5,p5) ST(r6,c6,v6,p6) ST(r7,c7,v7,p7)
    #undef ST
}

// ---------------------------------------------------------------------------
// Aggregate: one wave per row. lane j = feature j. Packed (col,val) loads are
// wave-uniform 8B broadcasts; sp gathers are coalesced 256B/edge. No atomics.
// ---------------------------------------------------------------------------
__global__ __launch_bounds__(256) void aggregate(
    const int2* __restrict__ edat, const u32* __restrict__ offsets,
    const float* __restrict__ sp, const float* __restrict__ bias,
    float* __restrict__ out, int n_nodes)
{
    const int wid = (blockIdx.x * 256 + threadIdx.x) >> 6;   // row
    const int lane = threadIdx.x & 63;
    if (wid >= n_nodes) return;
    const int beg = __builtin_amdgcn_readfirstlane((int)offsets[wid]);
    const int end = __builtin_amdgcn_readfirstlane((int)offsets[wid + 1]);

    float acc = bias[lane];
    int i = beg;
    for (; i + 1 < end; i += 2) {
        const int2 d0 = edat[i];
        const int2 d1 = edat[i + 1];
        const float s0 = sp[(size_t)d0.x * OUT_F + lane];
        const float s1 = sp[(size_t)d1.x * OUT_F + lane];
        acc += __int_as_float(d0.y) * s0;
        acc += __int_as_float(d1.y) * s1;
    }
    if (i < end) {
        const int2 d = edat[i];
        acc += __int_as_float(d.y) * sp[(size_t)d.x * OUT_F + lane];
    }
    out[(size_t)wid * OUT_F + lane] = acc;
}

// ---------------------------------------------------------------------------
extern "C" void kernel_launch(void* const* d_in, const int* in_sizes, int n_in,
                              void* d_out, int out_size, void* d_ws, size_t ws_size,
                              hipStream_t stream) {
    const float* x        = (const float*)d_in[0];
    const float* W        = (const float*)d_in[1];
    const float* bias     = (const float*)d_in[2];
    const int*   adj_rows = (const int*)d_in[3];
    const int*   adj_cols = (const int*)d_in[4];
    const float* adj_vals = (const float*)d_in[5];
    float* out = (float*)d_out;

    const int n_nodes = in_sizes[0] / IN_F;
    const int n_edges = in_sizes[3];

    // Workspace layout (edat first after sp for 8B alignment), ~33.2 MB:
    char* ws = (char*)d_ws;
    float* sp       = (float*)ws;                                   // n_nodes*64 f32
    int2*  edat     = (int2*)(ws + (size_t)n_nodes * OUT_F * 4);    // n_edges int2
    u32*   counts   = (u32*)(edat + n_edges);                       // n_nodes
    u32*   offsets  = counts + n_nodes;                             // n_nodes+1
    u32*   cursors  = offsets + n_nodes + 1;                        // n_nodes
    u32*   blockSums= cursors + n_nodes;                            // <=256

    // 1) sp = x @ W
    gemm_xw<<<(n_nodes + 63) / 64, 256, 0, stream>>>(x, W, sp, n_nodes);

    // 2) counting sort by row
    hipMemsetAsync(counts, 0, (size_t)n_nodes * 4, stream);
    hist_rows<<<(n_edges + 255) / 256, 256, 0, stream>>>(adj_rows, counts, n_edges);
    const int nb = (n_nodes + 2047) / 2048;
    scan1<<<nb, 256, 0, stream>>>(counts, offsets, blockSums, n_nodes);
    scan2<<<1, 256, 0, stream>>>(blockSums, nb);
    scan3<<<(n_nodes + 1 + 255) / 256, 256, 0, stream>>>(offsets, blockSums, cursors,
                                                         n_nodes, n_edges);
    const int ssBlocks = (n_edges + 256 * EPT - 1) / (256 * EPT);
    sort_scatter<<<ssBlocks, 256, 0, stream>>>(
        adj_rows, adj_cols, adj_vals, cursors, edat, n_edges);

    // 3) per-row gather-aggregate (bias folded in, no atomics)
    aggregate<<<(n_nodes + 3) / 4, 256, 0, stream>>>(
        edat, offsets, sp, bias, out, n_nodes);
}